// Round 5
// baseline (1397.669 us; speedup 1.0000x reference)
//
#include <hip/hip_runtime.h>
#include <stdint.h>

// ============================================================================
// GRU_Model: 2-layer bidirectional GRU, B=512 T=64 E=300 H=512, fp16 MFMA.
//
// Round-6 change (scan kernel only): data-as-flag exchange.
//  - revert to round-3 geometry (dual 16-row chains, resident Whh, 256 blocks,
//    1 block/CU) which measured best (375 us).
//  - h exchange: per-step buffer slots (64 slots x 1MB, 0xFF=NaN sentinel
//    prefill). Consumers poll the h words directly until != sentinel; the
//    data IS the flag. Removes per-step: vmcnt(0) store drain, flag store,
//    flag poll round trip, acquire fence.
//  - intra-block barriers use raw s_barrier + lgkmcnt(0) only (no vmcnt
//    drain) so h-stores stay in flight across barriers.
//  - same arithmetic and accumulation order -> bit-identical numerics.
// ============================================================================

#define NTW 192   // 3072/16 gate-column tiles (both dirs)
#define MTX 2048  // 32768/16 row tiles (B*T)

typedef _Float16 half8 __attribute__((ext_vector_type(8)));
typedef _Float16 half4_t __attribute__((ext_vector_type(4)));
typedef float float4_t __attribute__((ext_vector_type(4)));

__device__ __forceinline__ void gl_lds16(const void* g, void* l) {
  __builtin_amdgcn_global_load_lds(
      (const __attribute__((address_space(1))) void*)g,
      (__attribute__((address_space(3))) void*)l, 16, 0, 0);
}

__device__ __forceinline__ float sigm_f(float x) { return 1.f / (1.f + __expf(-x)); }
__device__ __forceinline__ float tanh_f(float x) { return 1.f - 2.f / (__expf(2.f * x) + 1.f); }

// LDS-only barrier: waits DS ops, leaves global stores in flight (no vmcnt).
__device__ __forceinline__ void ldsbar() {
  asm volatile("s_waitcnt lgkmcnt(0)" ::: "memory");
  __builtin_amdgcn_sched_barrier(0);
  __builtin_amdgcn_s_barrier();
}

// f32 (3072, K) row-major -> fp16 frag layout [192][KI][64][8], zero-pad to KI*32
__global__ void pack_b_kernel(const float* __restrict__ src, _Float16* __restrict__ dst,
                              int K, int KI) {
  int gid = blockIdx.x * 256 + threadIdx.x;
  int l = gid & 63, unit = gid >> 6;
  int nt = unit / KI, ks = unit - nt * KI;
  if (nt >= NTW) return;
  int row = nt * 16 + (l & 15);
  int col0 = ks * 32 + ((l >> 4) << 3);
  half8 v;
#pragma unroll
  for (int j = 0; j < 8; ++j) {
    int c = col0 + j;
    v[j] = (c < K) ? (_Float16)src[(long)row * K + c] : (_Float16)0.f;
  }
  *(half8*)(dst + (long)unit * 512 + l * 8) = v;
}

// embedding gather -> x0 frag layout [2048][10][64][8] (K=300 padded to 320)
__global__ void gather_kernel(const int* __restrict__ tokens, const float* __restrict__ emb,
                              _Float16* __restrict__ x0) {
  int gid = blockIdx.x * 256 + threadIdx.x;
  int l = gid & 63, unit = gid >> 6;
  int mt = unit / 10, ks = unit - mt * 10;
  if (mt >= MTX) return;
  int row = mt * 16 + (l & 15);  // row = b*64 + t
  const float* e = emb + (long)tokens[row] * 300;
  int col0 = ks * 32 + ((l >> 4) << 3);
  half8 v;
#pragma unroll
  for (int j = 0; j < 8; ++j) {
    int c = col0 + j;
    v[j] = (c < 300) ? (_Float16)e[c] : (_Float16)0.f;
  }
  *(half8*)(x0 + (long)unit * 512 + l * 8) = v;
}

// C(M=32768,N=3072) = A(M,K) * B(N,K)^T + bias[n];  A,B frag-layout fp16,
// C in C-frag tile layout [mtile][ntile][256] fp16.  grid (24, 256), 256 thr.
__global__ __launch_bounds__(256) void gemm_bt_kernel(
    const _Float16* __restrict__ A, const _Float16* __restrict__ Bw,
    const float* __restrict__ bias, _Float16* __restrict__ C, int KI) {
  __shared__ _Float16 As[8 * 512];
  __shared__ _Float16 Bs[8 * 512];
  const int bx = blockIdx.x, by = blockIdx.y;
  const int tid = threadIdx.x, w = tid >> 6, l = tid & 63;
  const int wm = w >> 1, wn = w & 1, ln = l & 15;
  const int mt0 = by * 8, nt0 = bx * 8;
  float4_t acc[4][4];
#pragma unroll
  for (int i = 0; i < 4; ++i)
#pragma unroll
    for (int j = 0; j < 4; ++j) acc[i][j] = 0.f;
  for (int it = 0; it < KI; ++it) {
    __syncthreads();  // protect LDS from previous iter's readers
    gl_lds16(A + ((long)(mt0 + w) * KI + it) * 512 + l * 8, As + w * 512 + l * 8);
    gl_lds16(A + ((long)(mt0 + w + 4) * KI + it) * 512 + l * 8, As + (w + 4) * 512 + l * 8);
    gl_lds16(Bw + ((long)(nt0 + w) * KI + it) * 512 + l * 8, Bs + w * 512 + l * 8);
    gl_lds16(Bw + ((long)(nt0 + w + 4) * KI + it) * 512 + l * 8, Bs + (w + 4) * 512 + l * 8);
    __syncthreads();  // compiler emits vmcnt(0) drain
    half8 af[4], bf[4];
#pragma unroll
    for (int i = 0; i < 4; ++i) af[i] = *(const half8*)(As + (wm * 4 + i) * 512 + l * 8);
#pragma unroll
    for (int j = 0; j < 4; ++j) bf[j] = *(const half8*)(Bs + (wn * 4 + j) * 512 + l * 8);
#pragma unroll
    for (int i = 0; i < 4; ++i)
#pragma unroll
      for (int j = 0; j < 4; ++j)
        acc[i][j] = __builtin_amdgcn_mfma_f32_16x16x32_f16(af[i], bf[j], acc[i][j], 0, 0, 0);
  }
#pragma unroll
  for (int i = 0; i < 4; ++i)
#pragma unroll
    for (int j = 0; j < 4; ++j) {
      int mt = mt0 + wm * 4 + i, ntile = nt0 + wn * 4 + j;
      float bv = bias[ntile * 16 + ln];
      half4_t o;
#pragma unroll
      for (int r = 0; r < 4; ++r) o[r] = (_Float16)(acc[i][j][r] + bv);
      *(half4_t*)(C + ((long)mt * NTW + ntile) * 256 + l * 4) = o;  // coalesced 8B
    }
}

// Persistent bidirectional GRU scan over 64 steps, dual 16-row chains/block.
// grid 256 = d(2) x mp(16) x ntb(8). Chains: rowtiles rA=2mp, rB=2mp+1.
// hbuf: [d(2)][step(64)][32 rowtiles][16 colfrags][1KB] fp16 frag layout;
// slot (d,0) zero-filled (h0=0), slots (d,1..63) 0xFF sentinel-filled.
// Sync: consumers poll h words directly until != 0xFFFF... (fp16 NaN, which
// bounded h never produces). No flags, no fences, no store drains.
__global__ __launch_bounds__(256, 1) void gru_scan_kernel(
    const _Float16* __restrict__ whh,  // [192][16][64][8]
    const float* __restrict__ bhh,     // [3072]
    const _Float16* __restrict__ gx,   // [2048][192][256] (C-frag tiles)
    _Float16* hbuf, _Float16* ys,      // ys: x1 frag [2048][32][64][8] or null
    float* last) {                     // [512][1024] f32 or null
  __shared__ alignas(16) _Float16 hsA[16 * 512];  // 16KB chain-A h (frag layout)
  __shared__ alignas(16) _Float16 hsB[16 * 512];  // 16KB chain-B h
  __shared__ alignas(16) _Float16 hx[2 * 512];    // 2KB transpose buf (shared A/B)
  const int bid = blockIdx.x;
  const int d = bid >> 7, mp = (bid >> 3) & 15, ntb = bid & 7;
  const int rA = mp * 2, rB = rA + 1;
  const int tid = threadIdx.x, w = tid >> 6, l = tid & 63;
  const int lq = l >> 4, ln = l & 15;
  const int hcol = ntb * 64 + w * 16 + ln;  // this lane's h column

  // Whh slice resident for all 64 steps (48 frags, shared by both chains)
  half8 bf[3][16];
#pragma unroll
  for (int g = 0; g < 3; ++g) {
    const int tg = d * 96 + g * 32 + ntb * 4 + w;
#pragma unroll
    for (int ks = 0; ks < 16; ++ks)
      bf[g][ks] = *(const half8*)(whh + (long)(tg * 16 + ks) * 512 + l * 8);
  }
  const float bh0 = bhh[d * 1536 + hcol];
  const float bh1 = bhh[d * 1536 + 512 + hcol];
  const float bh2 = bhh[d * 1536 + 1024 + hcol];
  float hrA[4] = {0.f, 0.f, 0.f, 0.f};  // fp32 master h, chain A
  float hrB[4] = {0.f, 0.f, 0.f, 0.f};  // fp32 master h, chain B
  const int ntg0 = d * 96 + ntb * 4 + w;
  const unsigned long long* hb8 = (const unsigned long long*)hbuf;
  unsigned long long* hb8w = (unsigned long long*)hbuf;
  unsigned long long* lA64 = (unsigned long long*)hsA;
  unsigned long long* lB64 = (unsigned long long*)hsB;
  const unsigned long long* hx64 = (const unsigned long long*)hx;
  const unsigned long long SENT = ~0ULL;  // 4x fp16 NaN

  float xrA[4], xzA[4], xnA[4], xrB[4], xzB[4], xnB[4];
  auto load_gx = [&](int step, int rc, float (&vr)[4], float (&vz)[4], float (&vn)[4]) {
    const int t2 = d ? (63 - step) : step;
    const int rm2 = t2 & 15, tq2 = t2 >> 4;
    const int eoff2 = ((rm2 >> 2) * 16 + ln) * 4 + (rm2 & 3);
#pragma unroll
    for (int r = 0; r < 4; ++r) {
      const int b = rc * 16 + lq * 4 + r;
      const long gbase = ((long)(b * 4 + tq2) * 192 + ntg0) * 256 + eoff2;
      vr[r] = (float)gx[gbase];
      vz[r] = (float)gx[gbase + 32 * 256];
      vn[r] = (float)gx[gbase + 64 * 256];
    }
  };
  load_gx(0, rA, xrA, xzA, xnA);  // prologue: step-0 gx, both chains
  load_gx(0, rB, xrB, xzB, xnB);

  // poll-load 8 words: issue all, then respin only the unset ones
  auto poll8 = [&](const unsigned long long* src, unsigned long long (&t)[8]) {
#pragma unroll
    for (int j = 0; j < 8; ++j)
      t[j] = __hip_atomic_load(src + j * 256 + tid, __ATOMIC_RELAXED,
                               __HIP_MEMORY_SCOPE_AGENT);
#pragma unroll
    for (int j = 0; j < 8; ++j) {
      long guard = 0;
      while (t[j] == SENT) {
        __builtin_amdgcn_s_sleep(1);
        t[j] = __hip_atomic_load(src + j * 256 + tid, __ATOMIC_RELAXED,
                                 __HIP_MEMORY_SCOPE_AGENT);
        if (++guard > (1L << 24)) break;  // bail out instead of hanging forever
      }
    }
  };

  for (int s = 0; s < 64; ++s) {
    const int t_in = d ? (63 - s) : s;
    const int rm = t_in & 15, tq = t_in >> 4;
    const unsigned long long* slot = hb8 + (long)(d * 64 + s) * 65536;

    // ---- chain A: poll h(s), stage to LDS ----
    unsigned long long ta[8];
    poll8(slot + (long)rA * 2048, ta);
#pragma unroll
    for (int j = 0; j < 8; ++j) lA64[j * 256 + tid] = ta[j];
    ldsbar();  // hsA staged (h stores from prev step stay in flight)

    // ---- chain A MFMA ----
    float4_t accA[3];
    accA[0] = 0.f; accA[1] = 0.f; accA[2] = 0.f;
#pragma unroll
    for (int kk = 0; kk < 2; ++kk) {
      half8 af[8];
#pragma unroll
      for (int k2 = 0; k2 < 8; ++k2)
        af[k2] = *(const half8*)(hsA + (kk * 8 + k2) * 512 + l * 8);
#pragma unroll
      for (int k2 = 0; k2 < 8; ++k2)
#pragma unroll
        for (int g = 0; g < 3; ++g)
          accA[g] = __builtin_amdgcn_mfma_f32_16x16x32_f16(af[k2], bf[g][kk * 8 + k2],
                                                           accA[g], 0, 0, 0);
    }

    // ---- chain B: poll h(s) (overlaps A MFMA latency), stage to LDS ----
    unsigned long long tb[8];
    poll8(slot + (long)rB * 2048, tb);
#pragma unroll
    for (int j = 0; j < 8; ++j) lB64[j * 256 + tid] = tb[j];

    // ---- chain A gates ----
#pragma unroll
    for (int r = 0; r < 4; ++r) {
      const int b = rA * 16 + lq * 4 + r;
      const long gmt = (long)b * 4 + tq;
      const float rg = sigm_f(xrA[r] + accA[0][r] + bh0);
      const float zg = sigm_f(xzA[r] + accA[1][r] + bh1);
      const float ng = tanh_f(xnA[r] + rg * (accA[2][r] + bh2));
      const float hv = (1.f - zg) * ng + zg * hrA[r];
      hrA[r] = hv;
      hx[(w >> 1) * 512 + (((w & 1) * 2 + (ln >> 3)) * 16 + lq * 4 + r) * 8 + (ln & 7)] =
          (_Float16)hv;
      if (ys != nullptr) {
        const int kcol = d * 512 + hcol;
        ys[(gmt * 32 + (kcol >> 5)) * 512 + (((kcol >> 3) & 3) * 16 + rm) * 8 + (kcol & 7)] =
            (_Float16)hv;
      }
      if (last != nullptr && ((d == 0 && s == 63) || (d == 1 && s == 0)))
        last[(long)b * 1024 + d * 512 + hcol] = hv;
    }
    ldsbar();  // hsB staged + hxA visible

    if (s < 63) {  // store chain A h(s+1) into slot s+1; no drain, no flag
      const unsigned long long qa = hx64[tid];
      unsigned long long* dst = hb8w + (long)(d * 64 + s + 1) * 65536 +
                                (long)rA * 2048 + (ntb * 2 + (tid >> 7)) * 128 + (tid & 127);
      __hip_atomic_store(dst, qa, __ATOMIC_RELAXED, __HIP_MEMORY_SCOPE_AGENT);
    }

    // ---- chain B MFMA (overlaps A's store flight) ----
    float4_t accB[3];
    accB[0] = 0.f; accB[1] = 0.f; accB[2] = 0.f;
#pragma unroll
    for (int kk = 0; kk < 2; ++kk) {
      half8 af[8];
#pragma unroll
      for (int k2 = 0; k2 < 8; ++k2)
        af[k2] = *(const half8*)(hsB + (kk * 8 + k2) * 512 + l * 8);
#pragma unroll
      for (int k2 = 0; k2 < 8; ++k2)
#pragma unroll
        for (int g = 0; g < 3; ++g)
          accB[g] = __builtin_amdgcn_mfma_f32_16x16x32_f16(af[k2], bf[g][kk * 8 + k2],
                                                           accB[g], 0, 0, 0);
    }
    ldsbar();  // all hx reads (A store) done before B's gates rewrite hx

    // ---- chain B gates ----
#pragma unroll
    for (int r = 0; r < 4; ++r) {
      const int b = rB * 16 + lq * 4 + r;
      const long gmt = (long)b * 4 + tq;
      const float rg = sigm_f(xrB[r] + accB[0][r] + bh0);
      const float zg = sigm_f(xzB[r] + accB[1][r] + bh1);
      const float ng = tanh_f(xnB[r] + rg * (accB[2][r] + bh2));
      const float hv = (1.f - zg) * ng + zg * hrB[r];
      hrB[r] = hv;
      hx[(w >> 1) * 512 + (((w & 1) * 2 + (ln >> 3)) * 16 + lq * 4 + r) * 8 + (ln & 7)] =
          (_Float16)hv;
      if (ys != nullptr) {
        const int kcol = d * 512 + hcol;
        ys[(gmt * 32 + (kcol >> 5)) * 512 + (((kcol >> 3) & 3) * 16 + rm) * 8 + (kcol & 7)] =
            (_Float16)hv;
      }
      if (last != nullptr && ((d == 0 && s == 63) || (d == 1 && s == 0)))
        last[(long)b * 1024 + d * 512 + hcol] = hv;
    }
    if (s == 63) break;  // last h never consumed

    ldsbar();  // hxB visible
    {          // store chain B h(s+1)
      const unsigned long long qb = hx64[tid];
      unsigned long long* dst = hb8w + (long)(d * 64 + s + 1) * 65536 +
                                (long)rB * 2048 + (ntb * 2 + (tid >> 7)) * 128 + (tid & 127);
      __hip_atomic_store(dst, qb, __ATOMIC_RELAXED, __HIP_MEMORY_SCOPE_AGENT);
    }

    // prefetch next step's gx for both chains (flies during next poll)
    load_gx(s + 1, rA, xrA, xzA, xnA);
    load_gx(s + 1, rB, xrB, xzB, xnB);
  }
}

// out[b][o] = last[b] . fc_w[o] + fc_b[o];  512 blocks x 1 wave
__global__ void fc_kernel(const float* __restrict__ lastb, const float* __restrict__ fw,
                          const float* __restrict__ fb, float* __restrict__ out) {
  const int b = blockIdx.x, l = threadIdx.x;
  const float* x = lastb + (long)b * 1024;
  float a0 = 0.f, a1 = 0.f;
  for (int k = l; k < 1024; k += 64) {
    const float v = x[k];
    a0 += v * fw[k];
    a1 += v * fw[1024 + k];
  }
#pragma unroll
  for (int off = 32; off > 0; off >>= 1) {
    a0 += __shfl_down(a0, off, 64);
    a1 += __shfl_down(a1, off, 64);
  }
  if (l == 0) {
    out[b * 2 + 0] = a0 + fb[0];
    out[b * 2 + 1] = a1 + fb[1];
  }
}

extern "C" void kernel_launch(void* const* d_in, const int* in_sizes, int n_in,
                              void* d_out, int out_size, void* d_ws, size_t ws_size,
                              hipStream_t stream) {
  const int* tokens = (const int*)d_in[0];
  const float* emb = (const float*)d_in[1];
  const float* w_ih0 = (const float*)d_in[2];
  const float* w_hh0 = (const float*)d_in[3];
  const float* b_ih0 = (const float*)d_in[4];
  const float* b_hh0 = (const float*)d_in[5];
  const float* w_ih1 = (const float*)d_in[6];
  const float* w_hh1 = (const float*)d_in[7];
  const float* b_ih1 = (const float*)d_in[8];
  const float* b_hh1 = (const float*)d_in[9];
  const float* fc_w = (const float*)d_in[10];
  const float* fc_b = (const float*)d_in[11];
  float* out = (float*)d_out;

  char* ws = (char*)d_ws;
  size_t off = 0;
  auto alloc = [&](size_t bytes) -> void* {
    void* p = ws + off;
    off += (bytes + 255) & ~(size_t)255;
    return p;
  };
  const size_t HSLOT = 65536UL * 8;  // 512 KB per (d,step) h slot
  _Float16* W0f = (_Float16*)alloc(192L * 10 * 512 * 2);   // w_ih0 frags (K 300->320)
  _Float16* W1f = (_Float16*)alloc(192L * 32 * 512 * 2);   // w_ih1 frags (K=1024)
  _Float16* Wh0f = (_Float16*)alloc(192L * 16 * 512 * 2);  // w_hh0 frags
  _Float16* Wh1f = (_Float16*)alloc(192L * 16 * 512 * 2);  // w_hh1 frags
  _Float16* x0f = (_Float16*)alloc(2048L * 10 * 512 * 2);  // embedded input frags
  _Float16* x1f = (_Float16*)alloc(2048L * 32 * 512 * 2);  // layer-0 output frags
  _Float16* gxb = (_Float16*)alloc(2048L * 192 * 256 * 2); // gx (shared L0/L1)
  _Float16* hbuf = (_Float16*)alloc(128UL * HSLOT);        // [d][64 steps] h slots, 64MB
  float* lastb = (float*)alloc(512L * 1024 * 4);
  if (off > ws_size) return;  // workspace too small -> visible absmax failure

  pack_b_kernel<<<dim3(192 * 10 * 64 / 256), 256, 0, stream>>>(w_ih0, W0f, 300, 10);
  pack_b_kernel<<<dim3(192 * 32 * 64 / 256), 256, 0, stream>>>(w_ih1, W1f, 1024, 32);
  pack_b_kernel<<<dim3(192 * 16 * 64 / 256), 256, 0, stream>>>(w_hh0, Wh0f, 512, 16);
  pack_b_kernel<<<dim3(192 * 16 * 64 / 256), 256, 0, stream>>>(w_hh1, Wh1f, 512, 16);
  gather_kernel<<<dim3(2048 * 10 * 64 / 256), 256, 0, stream>>>(tokens, emb, x0f);

  gemm_bt_kernel<<<dim3(24, 256), 256, 0, stream>>>(x0f, W0f, b_ih0, gxb, 10);
  // sentinel-fill all slots, zero-fill h(0) slot of each direction
  hipMemsetAsync(hbuf, 0xFF, 128UL * HSLOT, stream);
  hipMemsetAsync((char*)hbuf, 0, HSLOT, stream);                // d=0, s=0
  hipMemsetAsync((char*)hbuf + 64UL * HSLOT, 0, HSLOT, stream); // d=1, s=0
  gru_scan_kernel<<<dim3(256), 256, 0, stream>>>(Wh0f, b_hh0, gxb, hbuf, x1f, nullptr);

  gemm_bt_kernel<<<dim3(24, 256), 256, 0, stream>>>(x1f, W1f, b_ih1, gxb, 32);
  hipMemsetAsync(hbuf, 0xFF, 128UL * HSLOT, stream);
  hipMemsetAsync((char*)hbuf, 0, HSLOT, stream);
  hipMemsetAsync((char*)hbuf + 64UL * HSLOT, 0, HSLOT, stream);
  gru_scan_kernel<<<dim3(256), 256, 0, stream>>>(Wh1f, b_hh1, gxb, hbuf, nullptr, lastb);

  fc_kernel<<<dim3(512), 64, 0, stream>>>(lastb, fc_w, fc_b, out);
}

// Round 6
// 1254.605 us; speedup vs baseline: 1.1140x; 1.1140x over previous
//
#include <hip/hip_runtime.h>
#include <stdint.h>

// ============================================================================
// GRU_Model: 2-layer bidirectional GRU, B=512 T=64 E=300 H=512, fp16 MFMA.
//
// Round-6 change: back to round-3 skeleton (dual 16-row chains, flags, 375us)
// plus two coordinated fixes:
//  1) vmcnt-FIFO-safe scheduling: gx loads are issued AFTER the h loads each
//     iteration (sched_barrier-pinned), so staging's counted vmcnt waits on h
//     only and never force-drains in-flight gx HBM loads. Stage/transpose
//     barriers are lgkmcnt-only (ldsbar); full __syncthreads retained only
//     before the two flag stores (store-visibility), with chain-B MFMA
//     covering chain-A's store drain.
//  2) M-reorder: M = t*512 + b (was b*64+t). gather/GEMM-C/ys re-indexed so
//     the scan reads gx as 3x8B vector loads per chain from [t][col][b]
//     layout (was 12 scalar 2B loads), full 64B line use across chains.
// Same arithmetic and accumulation order -> bit-identical numerics.
// ============================================================================

#define NTW 192   // 3072/16 gate-column tiles (both dirs)
#define MTX 2048  // 32768/16 row tiles (B*T)

typedef _Float16 half8 __attribute__((ext_vector_type(8)));
typedef _Float16 half4_t __attribute__((ext_vector_type(4)));
typedef float float4_t __attribute__((ext_vector_type(4)));

__device__ __forceinline__ void gl_lds16(const void* g, void* l) {
  __builtin_amdgcn_global_load_lds(
      (const __attribute__((address_space(1))) void*)g,
      (__attribute__((address_space(3))) void*)l, 16, 0, 0);
}

__device__ __forceinline__ float sigm_f(float x) { return 1.f / (1.f + __expf(-x)); }
__device__ __forceinline__ float tanh_f(float x) { return 1.f - 2.f / (__expf(2.f * x) + 1.f); }

// LDS-only barrier: waits DS ops, leaves global loads/stores in flight.
__device__ __forceinline__ void ldsbar() {
  asm volatile("s_waitcnt lgkmcnt(0)" ::: "memory");
  __builtin_amdgcn_sched_barrier(0);
  __builtin_amdgcn_s_barrier();
}

// f32 (3072, K) row-major -> fp16 frag layout [192][KI][64][8], zero-pad to KI*32
__global__ void pack_b_kernel(const float* __restrict__ src, _Float16* __restrict__ dst,
                              int K, int KI) {
  int gid = blockIdx.x * 256 + threadIdx.x;
  int l = gid & 63, unit = gid >> 6;
  int nt = unit / KI, ks = unit - nt * KI;
  if (nt >= NTW) return;
  int row = nt * 16 + (l & 15);
  int col0 = ks * 32 + ((l >> 4) << 3);
  half8 v;
#pragma unroll
  for (int j = 0; j < 8; ++j) {
    int c = col0 + j;
    v[j] = (c < K) ? (_Float16)src[(long)row * K + c] : (_Float16)0.f;
  }
  *(half8*)(dst + (long)unit * 512 + l * 8) = v;
}

// embedding gather -> x0 frag layout [2048][10][64][8] (K=300 padded to 320).
// M dim is now t*512 + b  (t = row>>9, b = row&511).
__global__ void gather_kernel(const int* __restrict__ tokens, const float* __restrict__ emb,
                              _Float16* __restrict__ x0) {
  int gid = blockIdx.x * 256 + threadIdx.x;
  int l = gid & 63, unit = gid >> 6;
  int mt = unit / 10, ks = unit - mt * 10;
  if (mt >= MTX) return;
  int row = mt * 16 + (l & 15);  // row = t*512 + b
  int b = row & 511, t = row >> 9;
  const float* e = emb + (long)tokens[b * 64 + t] * 300;
  int col0 = ks * 32 + ((l >> 4) << 3);
  half8 v;
#pragma unroll
  for (int j = 0; j < 8; ++j) {
    int c = col0 + j;
    v[j] = (c < 300) ? (_Float16)e[c] : (_Float16)0.f;
  }
  *(half8*)(x0 + (long)unit * 512 + l * 8) = v;
}

// C(M=32768,N=3072) = A(M,K) * B(N,K)^T + bias[n];  A,B frag-layout fp16.
// C is written in scan layout G2[t(64)][col(3072)][b(512)] fp16: each thread's
// 4 accumulator rows are 4 consecutive b -> one 8B store; full lines are
// covered within the block across the i-loop.  grid (24, 256), 256 thr.
__global__ __launch_bounds__(256) void gemm_bt_kernel(
    const _Float16* __restrict__ A, const _Float16* __restrict__ Bw,
    const float* __restrict__ bias, _Float16* __restrict__ C, int KI) {
  __shared__ _Float16 As[8 * 512];
  __shared__ _Float16 Bs[8 * 512];
  const int bx = blockIdx.x, by = blockIdx.y;
  const int tid = threadIdx.x, w = tid >> 6, l = tid & 63;
  const int wm = w >> 1, wn = w & 1, ln = l & 15, lq = l >> 4;
  const int mt0 = by * 8, nt0 = bx * 8;
  float4_t acc[4][4];
#pragma unroll
  for (int i = 0; i < 4; ++i)
#pragma unroll
    for (int j = 0; j < 4; ++j) acc[i][j] = 0.f;
  for (int it = 0; it < KI; ++it) {
    __syncthreads();  // protect LDS from previous iter's readers
    gl_lds16(A + ((long)(mt0 + w) * KI + it) * 512 + l * 8, As + w * 512 + l * 8);
    gl_lds16(A + ((long)(mt0 + w + 4) * KI + it) * 512 + l * 8, As + (w + 4) * 512 + l * 8);
    gl_lds16(Bw + ((long)(nt0 + w) * KI + it) * 512 + l * 8, Bs + w * 512 + l * 8);
    gl_lds16(Bw + ((long)(nt0 + w + 4) * KI + it) * 512 + l * 8, Bs + (w + 4) * 512 + l * 8);
    __syncthreads();  // compiler emits vmcnt(0) drain
    half8 af[4], bf[4];
#pragma unroll
    for (int i = 0; i < 4; ++i) af[i] = *(const half8*)(As + (wm * 4 + i) * 512 + l * 8);
#pragma unroll
    for (int j = 0; j < 4; ++j) bf[j] = *(const half8*)(Bs + (wn * 4 + j) * 512 + l * 8);
#pragma unroll
    for (int i = 0; i < 4; ++i)
#pragma unroll
      for (int j = 0; j < 4; ++j)
        acc[i][j] = __builtin_amdgcn_mfma_f32_16x16x32_f16(af[i], bf[j], acc[i][j], 0, 0, 0);
  }
#pragma unroll
  for (int i = 0; i < 4; ++i)
#pragma unroll
    for (int j = 0; j < 4; ++j) {
      int mt = mt0 + wm * 4 + i, ntile = nt0 + wn * 4 + j;
      float bv = bias[ntile * 16 + ln];
      half4_t o;
#pragma unroll
      for (int r = 0; r < 4; ++r) o[r] = (_Float16)(acc[i][j][r] + bv);
      // G2[t][col][b]: t = mt>>5, col = ntile*16+ln, b = (mt&31)*16 + lq*4 (+r)
      *(half4_t*)(C + ((long)(mt >> 5) * 3072 + ntile * 16 + ln) * 512 +
                  (mt & 31) * 16 + lq * 4) = o;  // coalesced 8B
    }
}

// Persistent bidirectional GRU scan over 64 steps, dual 16-row chains/block.
// grid 256 = d(2) x mp(16) x ntb(8). Chains: rowtiles rA=2mp, rB=2mp+1.
// hbuf: [d*2+parity][32 rowtiles][16 colfrags][1KB] fp16 frag layout.
// Barrier: per (d,rowtile) flag group, 8 producers (ntb), relaxed sc1.
// Issue order per iter: poll -> h loads -> gx loads -> stage (vmcnt FIFO safe).
__global__ __launch_bounds__(256, 1) void gru_scan_kernel(
    const _Float16* __restrict__ whh,  // [192][16][64][8]
    const float* __restrict__ bhh,     // [3072]
    const _Float16* __restrict__ gx,   // [64 t][3072 col][512 b]
    _Float16* hbuf, _Float16* ys,      // ys: x1 frag [2048][32][64][8] or null
    float* last,                       // [512][1024] f32 or null
    unsigned int* cnt) {               // 64 groups x 16 flags, 64B/group
  __shared__ alignas(16) _Float16 hsA[16 * 512];  // 16KB chain-A h (frag layout)
  __shared__ alignas(16) _Float16 hsB[16 * 512];  // 16KB chain-B h
  __shared__ alignas(16) _Float16 hxA[1024];      // 2KB transpose buf, chain A
  __shared__ alignas(16) _Float16 hxB[1024];      // 2KB transpose buf, chain B
  const int bid = blockIdx.x;
  const int d = bid >> 7, mp = (bid >> 3) & 15, ntb = bid & 7;
  const int rA = mp * 2, rB = rA + 1;
  const int tid = threadIdx.x, w = tid >> 6, l = tid & 63;
  const int lq = l >> 4, ln = l & 15;
  unsigned int* flagsA = cnt + (d * 32 + rA) * 16;
  unsigned int* flagsB = cnt + (d * 32 + rB) * 16;
  const int hcol = ntb * 64 + w * 16 + ln;  // this lane's h column

  // Whh slice resident for all 64 steps (48 frags, shared by both chains)
  half8 bf[3][16];
#pragma unroll
  for (int g = 0; g < 3; ++g) {
    const int tg = d * 96 + g * 32 + ntb * 4 + w;
#pragma unroll
    for (int ks = 0; ks < 16; ++ks)
      bf[g][ks] = *(const half8*)(whh + (long)(tg * 16 + ks) * 512 + l * 8);
  }
  const float bh0 = bhh[d * 1536 + hcol];
  const float bh1 = bhh[d * 1536 + 512 + hcol];
  const float bh2 = bhh[d * 1536 + 1024 + hcol];
  float hrA[4] = {0.f, 0.f, 0.f, 0.f};  // fp32 master h, chain A
  float hrB[4] = {0.f, 0.f, 0.f, 0.f};  // fp32 master h, chain B
  const unsigned long long* hb8 = (const unsigned long long*)hbuf;
  unsigned long long* hb8w = (unsigned long long*)hbuf;
  unsigned long long* lA64 = (unsigned long long*)hsA;
  unsigned long long* lB64 = (unsigned long long*)hsB;
  const unsigned long long* hxA64 = (const unsigned long long*)hxA;
  const unsigned long long* hxB64 = (const unsigned long long*)hxB;

  for (int s = 0; s < 64; ++s) {
    const int par = s & 1;
    const int t_in = d ? (63 - s) : s;
    const unsigned long long* src = hb8 + (long)(d * 2 + par) * 65536;

    // ---- poll both chains' producer flags ----
    {
      const unsigned int tgt = (unsigned int)s;
      long guard = 0;
      for (;;) {
        const unsigned int fa = __hip_atomic_load(flagsA + (l & 7), __ATOMIC_RELAXED,
                                                  __HIP_MEMORY_SCOPE_AGENT);
        const unsigned int fb = __hip_atomic_load(flagsB + (l & 7), __ATOMIC_RELAXED,
                                                  __HIP_MEMORY_SCOPE_AGENT);
        if (__all((int)(fa >= tgt && fb >= tgt))) break;
        __builtin_amdgcn_s_sleep(1);
        if (++guard > (1L << 24)) break;  // bail out instead of hanging forever
      }
    }
    __builtin_amdgcn_fence(__ATOMIC_ACQUIRE, "workgroup");  // cheap: no cache ops
    __builtin_amdgcn_sched_barrier(0);

    // ---- h loads FIRST (oldest in vmcnt FIFO) ----
    unsigned long long ta[8], tb[8];
#pragma unroll
    for (int j = 0; j < 8; ++j)
      ta[j] = __hip_atomic_load(src + (long)rA * 2048 + j * 256 + tid, __ATOMIC_RELAXED,
                                __HIP_MEMORY_SCOPE_AGENT);
#pragma unroll
    for (int j = 0; j < 8; ++j)
      tb[j] = __hip_atomic_load(src + (long)rB * 2048 + j * 256 + tid, __ATOMIC_RELAXED,
                                __HIP_MEMORY_SCOPE_AGENT);
    __builtin_amdgcn_sched_barrier(0);

    // ---- gx loads for THIS step (younger than h: staging won't drain them) ----
    half4_t gA[3], gB[3];
    {
      const long gb = ((long)t_in * 3072 + d * 1536 + hcol) * 512;
      const int bA = rA * 16 + lq * 4, bB = rB * 16 + lq * 4;
      gA[0] = *(const half4_t*)(gx + gb + bA);
      gA[1] = *(const half4_t*)(gx + gb + 512L * 512 + bA);
      gA[2] = *(const half4_t*)(gx + gb + 1024L * 512 + bA);
      gB[0] = *(const half4_t*)(gx + gb + bB);
      gB[1] = *(const half4_t*)(gx + gb + 512L * 512 + bB);
      gB[2] = *(const half4_t*)(gx + gb + 1024L * 512 + bB);
    }
    __builtin_amdgcn_sched_barrier(0);

    // ---- stage h to LDS (compiler inserts counted vmcnt for ta/tb only) ----
#pragma unroll
    for (int j = 0; j < 8; ++j) lA64[j * 256 + tid] = ta[j];
#pragma unroll
    for (int j = 0; j < 8; ++j) lB64[j * 256 + tid] = tb[j];
    ldsbar();  // hsA+hsB staged; gx loads stay in flight

    // ---- chain A MFMA ----
    float4_t accA[3];
    accA[0] = 0.f; accA[1] = 0.f; accA[2] = 0.f;
#pragma unroll
    for (int kk = 0; kk < 2; ++kk) {
      half8 af[8];
#pragma unroll
      for (int k2 = 0; k2 < 8; ++k2)
        af[k2] = *(const half8*)(hsA + (kk * 8 + k2) * 512 + l * 8);
#pragma unroll
      for (int k2 = 0; k2 < 8; ++k2)
#pragma unroll
        for (int g = 0; g < 3; ++g)
          accA[g] = __builtin_amdgcn_mfma_f32_16x16x32_f16(af[k2], bf[g][kk * 8 + k2],
                                                           accA[g], 0, 0, 0);
    }

    // ---- chain A gates ----
#pragma unroll
    for (int r = 0; r < 4; ++r) {
      const int b = rA * 16 + lq * 4 + r;
      const float rg = sigm_f((float)gA[0][r] + accA[0][r] + bh0);
      const float zg = sigm_f((float)gA[1][r] + accA[1][r] + bh1);
      const float ng = tanh_f((float)gA[2][r] + rg * (accA[2][r] + bh2));
      const float hv = (1.f - zg) * ng + zg * hrA[r];
      hrA[r] = hv;
      hxA[(w >> 1) * 512 + (((w & 1) * 2 + (ln >> 3)) * 16 + lq * 4 + r) * 8 + (ln & 7)] =
          (_Float16)hv;
      if (ys != nullptr) {  // layer-0: emit x1 in frag layout (KI=32, M=t*512+b)
        const int kcol = d * 512 + hcol;
        ys[((long)(t_in * 32 + rA) * 32 + (kcol >> 5)) * 512 +
           (((kcol >> 3) & 3) * 16 + lq * 4 + r) * 8 + (kcol & 7)] = (_Float16)hv;
      }
      if (last != nullptr && ((d == 0 && s == 63) || (d == 1 && s == 0)))
        last[(long)b * 1024 + d * 512 + hcol] = hv;
    }
    ldsbar();  // hxA visible

    if (s < 63) {  // store chain A h(s+1): 8B/thread coalesced sc1, no drain yet
      const unsigned long long qa = hxA64[tid];
      unsigned long long* dst = hb8w + (long)(d * 2 + (par ^ 1)) * 65536 +
                                (long)rA * 2048 + (ntb * 2 + (tid >> 7)) * 128 + (tid & 127);
      __hip_atomic_store(dst, qa, __ATOMIC_RELAXED, __HIP_MEMORY_SCOPE_AGENT);
    }

    // ---- chain B MFMA (covers chain A's store drain) ----
    float4_t accB[3];
    accB[0] = 0.f; accB[1] = 0.f; accB[2] = 0.f;
#pragma unroll
    for (int kk = 0; kk < 2; ++kk) {
      half8 af[8];
#pragma unroll
      for (int k2 = 0; k2 < 8; ++k2)
        af[k2] = *(const half8*)(hsB + (kk * 8 + k2) * 512 + l * 8);
#pragma unroll
      for (int k2 = 0; k2 < 8; ++k2)
#pragma unroll
        for (int g = 0; g < 3; ++g)
          accB[g] = __builtin_amdgcn_mfma_f32_16x16x32_f16(af[k2], bf[g][kk * 8 + k2],
                                                           accB[g], 0, 0, 0);
    }
    __syncthreads();  // vmcnt(0): chain A store at MALL (gx already consumed)
    if (tid == 0 && s < 63)  // early A flag: peers stage A while we finish B
      __hip_atomic_store(flagsA + ntb, (unsigned int)(s + 1), __ATOMIC_RELAXED,
                         __HIP_MEMORY_SCOPE_AGENT);

    // ---- chain B gates ----
#pragma unroll
    for (int r = 0; r < 4; ++r) {
      const int b = rB * 16 + lq * 4 + r;
      const float rg = sigm_f((float)gB[0][r] + accB[0][r] + bh0);
      const float zg = sigm_f((float)gB[1][r] + accB[1][r] + bh1);
      const float ng = tanh_f((float)gB[2][r] + rg * (accB[2][r] + bh2));
      const float hv = (1.f - zg) * ng + zg * hrB[r];
      hrB[r] = hv;
      hxB[(w >> 1) * 512 + (((w & 1) * 2 + (ln >> 3)) * 16 + lq * 4 + r) * 8 + (ln & 7)] =
          (_Float16)hv;
      if (ys != nullptr) {
        const int kcol = d * 512 + hcol;
        ys[((long)(t_in * 32 + rB) * 32 + (kcol >> 5)) * 512 +
           (((kcol >> 3) & 3) * 16 + lq * 4 + r) * 8 + (kcol & 7)] = (_Float16)hv;
      }
      if (last != nullptr && ((d == 0 && s == 63) || (d == 1 && s == 0)))
        last[(long)b * 1024 + d * 512 + hcol] = hv;
    }
    if (s == 63) break;  // last h never consumed

    ldsbar();  // hxB visible
    {          // store chain B h(s+1)
      const unsigned long long qb = hxB64[tid];
      unsigned long long* dst = hb8w + (long)(d * 2 + (par ^ 1)) * 65536 +
                                (long)rB * 2048 + (ntb * 2 + (tid >> 7)) * 128 + (tid & 127);
      __hip_atomic_store(dst, qb, __ATOMIC_RELAXED, __HIP_MEMORY_SCOPE_AGENT);
    }
    __syncthreads();  // vmcnt(0): chain B store at MALL
    if (tid == 0)
      __hip_atomic_store(flagsB + ntb, (unsigned int)(s + 1), __ATOMIC_RELAXED,
                         __HIP_MEMORY_SCOPE_AGENT);
  }
}

// out[b][o] = last[b] . fc_w[o] + fc_b[o];  512 blocks x 1 wave
__global__ void fc_kernel(const float* __restrict__ lastb, const float* __restrict__ fw,
                          const float* __restrict__ fb, float* __restrict__ out) {
  const int b = blockIdx.x, l = threadIdx.x;
  const float* x = lastb + (long)b * 1024;
  float a0 = 0.f, a1 = 0.f;
  for (int k = l; k < 1024; k += 64) {
    const float v = x[k];
    a0 += v * fw[k];
    a1 += v * fw[1024 + k];
  }
#pragma unroll
  for (int off = 32; off > 0; off >>= 1) {
    a0 += __shfl_down(a0, off, 64);
    a1 += __shfl_down(a1, off, 64);
  }
  if (l == 0) {
    out[b * 2 + 0] = a0 + fb[0];
    out[b * 2 + 1] = a1 + fb[1];
  }
}

extern "C" void kernel_launch(void* const* d_in, const int* in_sizes, int n_in,
                              void* d_out, int out_size, void* d_ws, size_t ws_size,
                              hipStream_t stream) {
  const int* tokens = (const int*)d_in[0];
  const float* emb = (const float*)d_in[1];
  const float* w_ih0 = (const float*)d_in[2];
  const float* w_hh0 = (const float*)d_in[3];
  const float* b_ih0 = (const float*)d_in[4];
  const float* b_hh0 = (const float*)d_in[5];
  const float* w_ih1 = (const float*)d_in[6];
  const float* w_hh1 = (const float*)d_in[7];
  const float* b_ih1 = (const float*)d_in[8];
  const float* b_hh1 = (const float*)d_in[9];
  const float* fc_w = (const float*)d_in[10];
  const float* fc_b = (const float*)d_in[11];
  float* out = (float*)d_out;

  char* ws = (char*)d_ws;
  size_t off = 0;
  auto alloc = [&](size_t bytes) -> void* {
    void* p = ws + off;
    off += (bytes + 255) & ~(size_t)255;
    return p;
  };
  _Float16* W0f = (_Float16*)alloc(192L * 10 * 512 * 2);   // w_ih0 frags (K 300->320)
  _Float16* W1f = (_Float16*)alloc(192L * 32 * 512 * 2);   // w_ih1 frags (K=1024)
  _Float16* Wh0f = (_Float16*)alloc(192L * 16 * 512 * 2);  // w_hh0 frags
  _Float16* Wh1f = (_Float16*)alloc(192L * 16 * 512 * 2);  // w_hh1 frags
  _Float16* x0f = (_Float16*)alloc(2048L * 10 * 512 * 2);  // embedded input frags
  _Float16* x1f = (_Float16*)alloc(2048L * 32 * 512 * 2);  // layer-0 output frags
  _Float16* gxb = (_Float16*)alloc(64L * 3072 * 512 * 2);  // gx [t][col][b] (shared L0/L1)
  char* hz = ws + off;                                     // memset region start
  _Float16* hbuf = (_Float16*)alloc(4L * 32 * 8192 * 2);   // h double-buffer, 2 dirs
  unsigned int* cnt = (unsigned int*)alloc(4096);          // group barrier flags
  const size_t hz_bytes = 4L * 32 * 8192 * 2 + 4096;
  float* lastb = (float*)alloc(512L * 1024 * 4);
  if (off > ws_size) return;  // workspace too small -> visible absmax failure

  pack_b_kernel<<<dim3(192 * 10 * 64 / 256), 256, 0, stream>>>(w_ih0, W0f, 300, 10);
  pack_b_kernel<<<dim3(192 * 32 * 64 / 256), 256, 0, stream>>>(w_ih1, W1f, 1024, 32);
  pack_b_kernel<<<dim3(192 * 16 * 64 / 256), 256, 0, stream>>>(w_hh0, Wh0f, 512, 16);
  pack_b_kernel<<<dim3(192 * 16 * 64 / 256), 256, 0, stream>>>(w_hh1, Wh1f, 512, 16);
  gather_kernel<<<dim3(2048 * 10 * 64 / 256), 256, 0, stream>>>(tokens, emb, x0f);

  gemm_bt_kernel<<<dim3(24, 256), 256, 0, stream>>>(x0f, W0f, b_ih0, gxb, 10);
  hipMemsetAsync(hz, 0, hz_bytes, stream);
  gru_scan_kernel<<<dim3(256), 256, 0, stream>>>(Wh0f, b_hh0, gxb, hbuf, x1f, nullptr, cnt);

  gemm_bt_kernel<<<dim3(24, 256), 256, 0, stream>>>(x1f, W1f, b_ih1, gxb, 32);
  hipMemsetAsync(hz, 0, hz_bytes, stream);
  gru_scan_kernel<<<dim3(256), 256, 0, stream>>>(Wh1f, b_hh1, gxb, hbuf, nullptr, lastb, cnt);

  fc_kernel<<<dim3(512), 64, 0, stream>>>(lastb, fc_w, fc_b, out);
}

// Round 7
// 1164.914 us; speedup vs baseline: 1.1998x; 1.0770x over previous
//
#include <hip/hip_runtime.h>
#include <stdint.h>

// ============================================================================
// GRU_Model: 2-layer bidirectional GRU, B=512 T=64 E=300 H=512, fp16 MFMA.
//
// Round-7 change: keep round-6's M-reorder (M = t*512 + b) + vmcnt-FIFO-safe
// scan, but revert the GEMM C-epilogue to the fully-coalesced frag-tile
// store ([mtile][ntile][256], 1KB/wave contiguous). With M-reordered rows,
// the scan reads gx DIRECTLY from frag tiles with perfect coalescing:
// thread l reads half4 at tile offset l*4 (64 lanes cover 512B contiguous).
// Round 6's custom [t][col][b] gx layout (32B chunks @1KB stride on both the
// GEMM store and scan load sides) is deleted.
// Same arithmetic and accumulation order -> bit-identical numerics.
// ============================================================================

#define NTW 192   // 3072/16 gate-column tiles (both dirs)
#define MTX 2048  // 32768/16 row tiles (B*T)

typedef _Float16 half8 __attribute__((ext_vector_type(8)));
typedef _Float16 half4_t __attribute__((ext_vector_type(4)));
typedef float float4_t __attribute__((ext_vector_type(4)));

__device__ __forceinline__ void gl_lds16(const void* g, void* l) {
  __builtin_amdgcn_global_load_lds(
      (const __attribute__((address_space(1))) void*)g,
      (__attribute__((address_space(3))) void*)l, 16, 0, 0);
}

__device__ __forceinline__ float sigm_f(float x) { return 1.f / (1.f + __expf(-x)); }
__device__ __forceinline__ float tanh_f(float x) { return 1.f - 2.f / (__expf(2.f * x) + 1.f); }

// LDS-only barrier: waits DS ops, leaves global loads/stores in flight.
__device__ __forceinline__ void ldsbar() {
  asm volatile("s_waitcnt lgkmcnt(0)" ::: "memory");
  __builtin_amdgcn_sched_barrier(0);
  __builtin_amdgcn_s_barrier();
}

// f32 (3072, K) row-major -> fp16 frag layout [192][KI][64][8], zero-pad to KI*32
__global__ void pack_b_kernel(const float* __restrict__ src, _Float16* __restrict__ dst,
                              int K, int KI) {
  int gid = blockIdx.x * 256 + threadIdx.x;
  int l = gid & 63, unit = gid >> 6;
  int nt = unit / KI, ks = unit - nt * KI;
  if (nt >= NTW) return;
  int row = nt * 16 + (l & 15);
  int col0 = ks * 32 + ((l >> 4) << 3);
  half8 v;
#pragma unroll
  for (int j = 0; j < 8; ++j) {
    int c = col0 + j;
    v[j] = (c < K) ? (_Float16)src[(long)row * K + c] : (_Float16)0.f;
  }
  *(half8*)(dst + (long)unit * 512 + l * 8) = v;
}

// embedding gather -> x0 frag layout [2048][10][64][8] (K=300 padded to 320).
// M dim is t*512 + b  (t = row>>9, b = row&511).
__global__ void gather_kernel(const int* __restrict__ tokens, const float* __restrict__ emb,
                              _Float16* __restrict__ x0) {
  int gid = blockIdx.x * 256 + threadIdx.x;
  int l = gid & 63, unit = gid >> 6;
  int mt = unit / 10, ks = unit - mt * 10;
  if (mt >= MTX) return;
  int row = mt * 16 + (l & 15);  // row = t*512 + b
  int b = row & 511, t = row >> 9;
  const float* e = emb + (long)tokens[b * 64 + t] * 300;
  int col0 = ks * 32 + ((l >> 4) << 3);
  half8 v;
#pragma unroll
  for (int j = 0; j < 8; ++j) {
    int c = col0 + j;
    v[j] = (c < 300) ? (_Float16)e[c] : (_Float16)0.f;
  }
  *(half8*)(x0 + (long)unit * 512 + l * 8) = v;
}

// C(M=32768,N=3072) = A(M,K) * B(N,K)^T + bias[n];  A,B frag-layout fp16,
// C in C-frag tile layout [mtile][ntile][256] fp16 (coalesced 1KB/wave).
// grid (24, 256), 256 thr.
__global__ __launch_bounds__(256) void gemm_bt_kernel(
    const _Float16* __restrict__ A, const _Float16* __restrict__ Bw,
    const float* __restrict__ bias, _Float16* __restrict__ C, int KI) {
  __shared__ _Float16 As[8 * 512];
  __shared__ _Float16 Bs[8 * 512];
  const int bx = blockIdx.x, by = blockIdx.y;
  const int tid = threadIdx.x, w = tid >> 6, l = tid & 63;
  const int wm = w >> 1, wn = w & 1, ln = l & 15;
  const int mt0 = by * 8, nt0 = bx * 8;
  float4_t acc[4][4];
#pragma unroll
  for (int i = 0; i < 4; ++i)
#pragma unroll
    for (int j = 0; j < 4; ++j) acc[i][j] = 0.f;
  for (int it = 0; it < KI; ++it) {
    __syncthreads();  // protect LDS from previous iter's readers
    gl_lds16(A + ((long)(mt0 + w) * KI + it) * 512 + l * 8, As + w * 512 + l * 8);
    gl_lds16(A + ((long)(mt0 + w + 4) * KI + it) * 512 + l * 8, As + (w + 4) * 512 + l * 8);
    gl_lds16(Bw + ((long)(nt0 + w) * KI + it) * 512 + l * 8, Bs + w * 512 + l * 8);
    gl_lds16(Bw + ((long)(nt0 + w + 4) * KI + it) * 512 + l * 8, Bs + (w + 4) * 512 + l * 8);
    __syncthreads();  // compiler emits vmcnt(0) drain
    half8 af[4], bf[4];
#pragma unroll
    for (int i = 0; i < 4; ++i) af[i] = *(const half8*)(As + (wm * 4 + i) * 512 + l * 8);
#pragma unroll
    for (int j = 0; j < 4; ++j) bf[j] = *(const half8*)(Bs + (wn * 4 + j) * 512 + l * 8);
#pragma unroll
    for (int i = 0; i < 4; ++i)
#pragma unroll
      for (int j = 0; j < 4; ++j)
        acc[i][j] = __builtin_amdgcn_mfma_f32_16x16x32_f16(af[i], bf[j], acc[i][j], 0, 0, 0);
  }
#pragma unroll
  for (int i = 0; i < 4; ++i)
#pragma unroll
    for (int j = 0; j < 4; ++j) {
      int mt = mt0 + wm * 4 + i, ntile = nt0 + wn * 4 + j;
      float bv = bias[ntile * 16 + ln];
      half4_t o;
#pragma unroll
      for (int r = 0; r < 4; ++r) o[r] = (_Float16)(acc[i][j][r] + bv);
      *(half4_t*)(C + ((long)mt * NTW + ntile) * 256 + l * 4) = o;  // coalesced 8B
    }
}

// Persistent bidirectional GRU scan over 64 steps, dual 16-row chains/block.
// grid 256 = d(2) x mp(16) x ntb(8). Chains: rowtiles rA=2mp, rB=2mp+1.
// hbuf: [d*2+parity][32 rowtiles][16 colfrags][1KB] fp16 frag layout.
// Barrier: per (d,rowtile) flag group, 8 producers (ntb), relaxed sc1.
// Issue order per iter: poll -> h loads -> gx loads -> stage (vmcnt FIFO safe).
// gx read straight from C-frag tiles: thread l loads half4 at tile offset
// l*4 -> 64 lanes cover 512B contiguous per gate (fully coalesced).
__global__ __launch_bounds__(256, 1) void gru_scan_kernel(
    const _Float16* __restrict__ whh,  // [192][16][64][8]
    const float* __restrict__ bhh,     // [3072]
    const _Float16* __restrict__ gx,   // [2048 mtile][192 ntile][256] C-frag
    _Float16* hbuf, _Float16* ys,      // ys: x1 frag [2048][32][64][8] or null
    float* last,                       // [512][1024] f32 or null
    unsigned int* cnt) {               // 64 groups x 16 flags, 64B/group
  __shared__ alignas(16) _Float16 hsA[16 * 512];  // 16KB chain-A h (frag layout)
  __shared__ alignas(16) _Float16 hsB[16 * 512];  // 16KB chain-B h
  __shared__ alignas(16) _Float16 hxA[1024];      // 2KB transpose buf, chain A
  __shared__ alignas(16) _Float16 hxB[1024];      // 2KB transpose buf, chain B
  const int bid = blockIdx.x;
  const int d = bid >> 7, mp = (bid >> 3) & 15, ntb = bid & 7;
  const int rA = mp * 2, rB = rA + 1;
  const int tid = threadIdx.x, w = tid >> 6, l = tid & 63;
  const int lq = l >> 4, ln = l & 15;
  unsigned int* flagsA = cnt + (d * 32 + rA) * 16;
  unsigned int* flagsB = cnt + (d * 32 + rB) * 16;
  const int hcol = ntb * 64 + w * 16 + ln;  // this lane's h column

  // Whh slice resident for all 64 steps (48 frags, shared by both chains)
  half8 bf[3][16];
#pragma unroll
  for (int g = 0; g < 3; ++g) {
    const int tg = d * 96 + g * 32 + ntb * 4 + w;
#pragma unroll
    for (int ks = 0; ks < 16; ++ks)
      bf[g][ks] = *(const half8*)(whh + (long)(tg * 16 + ks) * 512 + l * 8);
  }
  const float bh0 = bhh[d * 1536 + hcol];
  const float bh1 = bhh[d * 1536 + 512 + hcol];
  const float bh2 = bhh[d * 1536 + 1024 + hcol];
  float hrA[4] = {0.f, 0.f, 0.f, 0.f};  // fp32 master h, chain A
  float hrB[4] = {0.f, 0.f, 0.f, 0.f};  // fp32 master h, chain B
  const int ntg0 = d * 96 + ntb * 4 + w;  // gate-r ntile for this wave's cols
  const unsigned long long* hb8 = (const unsigned long long*)hbuf;
  unsigned long long* hb8w = (unsigned long long*)hbuf;
  unsigned long long* lA64 = (unsigned long long*)hsA;
  unsigned long long* lB64 = (unsigned long long*)hsB;
  const unsigned long long* hxA64 = (const unsigned long long*)hxA;
  const unsigned long long* hxB64 = (const unsigned long long*)hxB;

  for (int s = 0; s < 64; ++s) {
    const int par = s & 1;
    const int t_in = d ? (63 - s) : s;
    const unsigned long long* src = hb8 + (long)(d * 2 + par) * 65536;

    // ---- poll both chains' producer flags ----
    {
      const unsigned int tgt = (unsigned int)s;
      long guard = 0;
      for (;;) {
        const unsigned int fa = __hip_atomic_load(flagsA + (l & 7), __ATOMIC_RELAXED,
                                                  __HIP_MEMORY_SCOPE_AGENT);
        const unsigned int fb = __hip_atomic_load(flagsB + (l & 7), __ATOMIC_RELAXED,
                                                  __HIP_MEMORY_SCOPE_AGENT);
        if (__all((int)(fa >= tgt && fb >= tgt))) break;
        __builtin_amdgcn_s_sleep(1);
        if (++guard > (1L << 24)) break;  // bail out instead of hanging forever
      }
    }
    __builtin_amdgcn_fence(__ATOMIC_ACQUIRE, "workgroup");  // cheap: no cache ops
    __builtin_amdgcn_sched_barrier(0);

    // ---- h loads FIRST (oldest in vmcnt FIFO) ----
    unsigned long long ta[8], tb[8];
#pragma unroll
    for (int j = 0; j < 8; ++j)
      ta[j] = __hip_atomic_load(src + (long)rA * 2048 + j * 256 + tid, __ATOMIC_RELAXED,
                                __HIP_MEMORY_SCOPE_AGENT);
#pragma unroll
    for (int j = 0; j < 8; ++j)
      tb[j] = __hip_atomic_load(src + (long)rB * 2048 + j * 256 + tid, __ATOMIC_RELAXED,
                                __HIP_MEMORY_SCOPE_AGENT);
    __builtin_amdgcn_sched_barrier(0);

    // ---- gx loads for THIS step (younger than h: staging won't drain them).
    //      Frag-tile read: half4 at tile offset l*4, fully coalesced. ----
    half4_t gA[3], gB[3];
    {
      const long gbA = ((long)(t_in * 32 + rA) * 192 + ntg0) * 256 + l * 4;
      const long gbB = gbA + 192L * 256;  // rowtile rB = rA+1
      gA[0] = *(const half4_t*)(gx + gbA);
      gA[1] = *(const half4_t*)(gx + gbA + 32 * 256);
      gA[2] = *(const half4_t*)(gx + gbA + 64 * 256);
      gB[0] = *(const half4_t*)(gx + gbB);
      gB[1] = *(const half4_t*)(gx + gbB + 32 * 256);
      gB[2] = *(const half4_t*)(gx + gbB + 64 * 256);
    }
    __builtin_amdgcn_sched_barrier(0);

    // ---- stage h to LDS (compiler inserts counted vmcnt for ta/tb only) ----
#pragma unroll
    for (int j = 0; j < 8; ++j) lA64[j * 256 + tid] = ta[j];
#pragma unroll
    for (int j = 0; j < 8; ++j) lB64[j * 256 + tid] = tb[j];
    ldsbar();  // hsA+hsB staged; gx loads stay in flight

    // ---- chain A MFMA ----
    float4_t accA[3];
    accA[0] = 0.f; accA[1] = 0.f; accA[2] = 0.f;
#pragma unroll
    for (int kk = 0; kk < 2; ++kk) {
      half8 af[8];
#pragma unroll
      for (int k2 = 0; k2 < 8; ++k2)
        af[k2] = *(const half8*)(hsA + (kk * 8 + k2) * 512 + l * 8);
#pragma unroll
      for (int k2 = 0; k2 < 8; ++k2)
#pragma unroll
        for (int g = 0; g < 3; ++g)
          accA[g] = __builtin_amdgcn_mfma_f32_16x16x32_f16(af[k2], bf[g][kk * 8 + k2],
                                                           accA[g], 0, 0, 0);
    }

    // ---- chain A gates ----
#pragma unroll
    for (int r = 0; r < 4; ++r) {
      const int b = rA * 16 + lq * 4 + r;
      const float rg = sigm_f((float)gA[0][r] + accA[0][r] + bh0);
      const float zg = sigm_f((float)gA[1][r] + accA[1][r] + bh1);
      const float ng = tanh_f((float)gA[2][r] + rg * (accA[2][r] + bh2));
      const float hv = (1.f - zg) * ng + zg * hrA[r];
      hrA[r] = hv;
      hxA[(w >> 1) * 512 + (((w & 1) * 2 + (ln >> 3)) * 16 + lq * 4 + r) * 8 + (ln & 7)] =
          (_Float16)hv;
      if (ys != nullptr) {  // layer-0: emit x1 in frag layout (KI=32, M=t*512+b)
        const int kcol = d * 512 + hcol;
        ys[((long)(t_in * 32 + rA) * 32 + (kcol >> 5)) * 512 +
           (((kcol >> 3) & 3) * 16 + lq * 4 + r) * 8 + (kcol & 7)] = (_Float16)hv;
      }
      if (last != nullptr && ((d == 0 && s == 63) || (d == 1 && s == 0)))
        last[(long)b * 1024 + d * 512 + hcol] = hv;
    }
    ldsbar();  // hxA visible

    if (s < 63) {  // store chain A h(s+1): 8B/thread coalesced sc1, no drain yet
      const unsigned long long qa = hxA64[tid];
      unsigned long long* dst = hb8w + (long)(d * 2 + (par ^ 1)) * 65536 +
                                (long)rA * 2048 + (ntb * 2 + (tid >> 7)) * 128 + (tid & 127);
      __hip_atomic_store(dst, qa, __ATOMIC_RELAXED, __HIP_MEMORY_SCOPE_AGENT);
    }

    // ---- chain B MFMA (covers chain A's store drain) ----
    float4_t accB[3];
    accB[0] = 0.f; accB[1] = 0.f; accB[2] = 0.f;
#pragma unroll
    for (int kk = 0; kk < 2; ++kk) {
      half8 af[8];
#pragma unroll
      for (int k2 = 0; k2 < 8; ++k2)
        af[k2] = *(const half8*)(hsB + (kk * 8 + k2) * 512 + l * 8);
#pragma unroll
      for (int k2 = 0; k2 < 8; ++k2)
#pragma unroll
        for (int g = 0; g < 3; ++g)
          accB[g] = __builtin_amdgcn_mfma_f32_16x16x32_f16(af[k2], bf[g][kk * 8 + k2],
                                                           accB[g], 0, 0, 0);
    }
    __syncthreads();  // vmcnt(0): chain A store at MALL (gx already consumed)
    if (tid == 0 && s < 63)  // early A flag: peers stage A while we finish B
      __hip_atomic_store(flagsA + ntb, (unsigned int)(s + 1), __ATOMIC_RELAXED,
                         __HIP_MEMORY_SCOPE_AGENT);

    // ---- chain B gates ----
#pragma unroll
    for (int r = 0; r < 4; ++r) {
      const int b = rB * 16 + lq * 4 + r;
      const float rg = sigm_f((float)gB[0][r] + accB[0][r] + bh0);
      const float zg = sigm_f((float)gB[1][r] + accB[1][r] + bh1);
      const float ng = tanh_f((float)gB[2][r] + rg * (accB[2][r] + bh2));
      const float hv = (1.f - zg) * ng + zg * hrB[r];
      hrB[r] = hv;
      hxB[(w >> 1) * 512 + (((w & 1) * 2 + (ln >> 3)) * 16 + lq * 4 + r) * 8 + (ln & 7)] =
          (_Float16)hv;
      if (ys != nullptr) {
        const int kcol = d * 512 + hcol;
        ys[((long)(t_in * 32 + rB) * 32 + (kcol >> 5)) * 512 +
           (((kcol >> 3) & 3) * 16 + lq * 4 + r) * 8 + (kcol & 7)] = (_Float16)hv;
      }
      if (last != nullptr && ((d == 0 && s == 63) || (d == 1 && s == 0)))
        last[(long)b * 1024 + d * 512 + hcol] = hv;
    }
    if (s == 63) break;  // last h never consumed

    ldsbar();  // hxB visible
    {          // store chain B h(s+1)
      const unsigned long long qb = hxB64[tid];
      unsigned long long* dst = hb8w + (long)(d * 2 + (par ^ 1)) * 65536 +
                                (long)rB * 2048 + (ntb * 2 + (tid >> 7)) * 128 + (tid & 127);
      __hip_atomic_store(dst, qb, __ATOMIC_RELAXED, __HIP_MEMORY_SCOPE_AGENT);
    }
    __syncthreads();  // vmcnt(0): chain B store at MALL
    if (tid == 0)
      __hip_atomic_store(flagsB + ntb, (unsigned int)(s + 1), __ATOMIC_RELAXED,
                         __HIP_MEMORY_SCOPE_AGENT);
  }
}

// out[b][o] = last[b] . fc_w[o] + fc_b[o];  512 blocks x 1 wave
__global__ void fc_kernel(const float* __restrict__ lastb, const float* __restrict__ fw,
                          const float* __restrict__ fb, float* __restrict__ out) {
  const int b = blockIdx.x, l = threadIdx.x;
  const float* x = lastb + (long)b * 1024;
  float a0 = 0.f, a1 = 0.f;
  for (int k = l; k < 1024; k += 64) {
    const float v = x[k];
    a0 += v * fw[k];
    a1 += v * fw[1024 + k];
  }
#pragma unroll
  for (int off = 32; off > 0; off >>= 1) {
    a0 += __shfl_down(a0, off, 64);
    a1 += __shfl_down(a1, off, 64);
  }
  if (l == 0) {
    out[b * 2 + 0] = a0 + fb[0];
    out[b * 2 + 1] = a1 + fb[1];
  }
}

extern "C" void kernel_launch(void* const* d_in, const int* in_sizes, int n_in,
                              void* d_out, int out_size, void* d_ws, size_t ws_size,
                              hipStream_t stream) {
  const int* tokens = (const int*)d_in[0];
  const float* emb = (const float*)d_in[1];
  const float* w_ih0 = (const float*)d_in[2];
  const float* w_hh0 = (const float*)d_in[3];
  const float* b_ih0 = (const float*)d_in[4];
  const float* b_hh0 = (const float*)d_in[5];
  const float* w_ih1 = (const float*)d_in[6];
  const float* w_hh1 = (const float*)d_in[7];
  const float* b_ih1 = (const float*)d_in[8];
  const float* b_hh1 = (const float*)d_in[9];
  const float* fc_w = (const float*)d_in[10];
  const float* fc_b = (const float*)d_in[11];
  float* out = (float*)d_out;

  char* ws = (char*)d_ws;
  size_t off = 0;
  auto alloc = [&](size_t bytes) -> void* {
    void* p = ws + off;
    off += (bytes + 255) & ~(size_t)255;
    return p;
  };
  _Float16* W0f = (_Float16*)alloc(192L * 10 * 512 * 2);   // w_ih0 frags (K 300->320)
  _Float16* W1f = (_Float16*)alloc(192L * 32 * 512 * 2);   // w_ih1 frags (K=1024)
  _Float16* Wh0f = (_Float16*)alloc(192L * 16 * 512 * 2);  // w_hh0 frags
  _Float16* Wh1f = (_Float16*)alloc(192L * 16 * 512 * 2);  // w_hh1 frags
  _Float16* x0f = (_Float16*)alloc(2048L * 10 * 512 * 2);  // embedded input frags
  _Float16* x1f = (_Float16*)alloc(2048L * 32 * 512 * 2);  // layer-0 output frags
  _Float16* gxb = (_Float16*)alloc(2048L * 192 * 256 * 2); // gx C-frag tiles
  char* hz = ws + off;                                     // memset region start
  _Float16* hbuf = (_Float16*)alloc(4L * 32 * 8192 * 2);   // h double-buffer, 2 dirs
  unsigned int* cnt = (unsigned int*)alloc(4096);          // group barrier flags
  const size_t hz_bytes = 4L * 32 * 8192 * 2 + 4096;
  float* lastb = (float*)alloc(512L * 1024 * 4);
  if (off > ws_size) return;  // workspace too small -> visible absmax failure

  pack_b_kernel<<<dim3(192 * 10 * 64 / 256), 256, 0, stream>>>(w_ih0, W0f, 300, 10);
  pack_b_kernel<<<dim3(192 * 32 * 64 / 256), 256, 0, stream>>>(w_ih1, W1f, 1024, 32);
  pack_b_kernel<<<dim3(192 * 16 * 64 / 256), 256, 0, stream>>>(w_hh0, Wh0f, 512, 16);
  pack_b_kernel<<<dim3(192 * 16 * 64 / 256), 256, 0, stream>>>(w_hh1, Wh1f, 512, 16);
  gather_kernel<<<dim3(2048 * 10 * 64 / 256), 256, 0, stream>>>(tokens, emb, x0f);

  gemm_bt_kernel<<<dim3(24, 256), 256, 0, stream>>>(x0f, W0f, b_ih0, gxb, 10);
  hipMemsetAsync(hz, 0, hz_bytes, stream);
  gru_scan_kernel<<<dim3(256), 256, 0, stream>>>(Wh0f, b_hh0, gxb, hbuf, x1f, nullptr, cnt);

  gemm_bt_kernel<<<dim3(24, 256), 256, 0, stream>>>(x1f, W1f, b_ih1, gxb, 32);
  hipMemsetAsync(hz, 0, hz_bytes, stream);
  gru_scan_kernel<<<dim3(256), 256, 0, stream>>>(Wh1f, b_hh1, gxb, hbuf, nullptr, lastb, cnt);

  fc_kernel<<<dim3(512), 64, 0, stream>>>(lastb, fc_w, fc_b, out);
}